// Round 12
// baseline (1040.497 us; speedup 1.0000x reference)
//
#include <hip/hip_runtime.h>

// GRU B=256,T=2000,I=23,H=128 (gate order r,z,n) + mean over T.
// 1 batch row per block, 256 blocks (1/CU). 512 threads = 8 waves, 2/SIMD.
//
// v15 vs v11/v14: HALVE THE DS-PIPE LOAD.
// Diagnosis: VALUBusy is overstated ~2x by the gfx94x derived-counter
// formula on CDNA4 (SIMD-32: wave64 VALU = 2cy not 4cy); real VALU busy is
// ~32%, so the kernel is DS-pipe/latency bound. Per step each CU issued
// 8 waves x (8 ds_read_b128 + 1 ds_write) = 72 DS instr ~= 700cy of the
// ~1350cy step. v11's win (removing 24 swizzle DS ops) fits this model.
// Fix: raise h-reuse per loaded float from 3 gates to 6 -- each lane owns
// TWO rows (6 gates) over a 16-wide k-window:
//   kt = lane bits {0,1,3} in [0,8), k in [16kt,16kt+16)
//   jj = lane bits {2,4,5}; rows j0 = wid*16+jj*2, j1 = j0+1
//   slot i holds row j0 + (i ^ (l&1))  (slot-permuted -> fold has no selects)
// ds_read: 4 x b128/lane (was 8) -> 32 reads/CU (was 64).
// x row: ONE dwordx4 via v13's clamped window e0=min(3kt,19)+masks (was 6
// scalar loads). Fold = slot-swap xor1 + xor2 + xor8, all DPP, no DS hops.
// After fold each lane holds ITS row jr = j0+(l&1)'s complete r/z/ghn/gxn
// -> lane-local epilogue; lanes duplicated 4x over bits {1,3}; writer =
// (l & 10) == 0. Weights/lane unchanged (48 v2f h + 8 v2f x + 4 biases).
// h LDS [2][8][20]: bank map {0,20,8,28,16,4,24,12}+4c, conflict-free
// (verified 0-conflict in v13). Keeps: LDS-only barrier, depth-2 parity x
// prefetch, exp2 prescale, native packed v2f MACs.

#define Bb 256
#define Tt 2000
#define Ii 23
#define Hh 128

typedef float v2f __attribute__((ext_vector_type(2)));
typedef float v4f __attribute__((ext_vector_type(4)));
typedef float v4fu __attribute__((ext_vector_type(4), aligned(4)));

template <int N> struct ic { static constexpr int v = N; };

template <int ctrl>
__device__ __forceinline__ float dpp_movf(float v) {
    int r = __builtin_amdgcn_update_dpp(0, __builtin_bit_cast(int, v),
                                        ctrl, 0xf, 0xf, true);
    return __builtin_bit_cast(float, r);
}
__device__ __forceinline__ float fexp2(float x) {
#if __has_builtin(__builtin_amdgcn_exp2f)
    return __builtin_amdgcn_exp2f(x);
#else
    return exp2f(x);
#endif
}
__device__ __forceinline__ v2f pinv(v2f v) { asm("" : "+v"(v)); return v; }
__device__ __forceinline__ float pinf(float v) { asm("" : "+v"(v)); return v; }
// LDS-only barrier: does NOT drain vmcnt (x prefetch stays in flight).
__device__ __forceinline__ void bar_lds() {
    asm volatile("s_waitcnt lgkmcnt(0)\n\ts_barrier" ::: "memory");
}
// Native packed MAC: selects v_pk_fma_f32 (or 2 scalar fma) on gfx950.
__device__ __forceinline__ v2f nfma(v2f a, v2f b, v2f c) {
    return __builtin_elementwise_fma(a, b, c);
}
// Slot-packed fold over kt lane-bits {0,1,3}. acc slot i corresponds to
// row j0 + (i ^ (l&1)), so level 1 (xor1) both completes the k-pair and
// routes each lane its own row's sum; xor2/xor8 are symmetric self-folds.
// Pure DPP -- no DS pipe. Lane ends with the FULL k-sum for row j0+(l&1).
__device__ __forceinline__ float sfold(v2f a0, v2f a1) {
    const float A0 = a0[0] + a0[1];
    const float A1 = a1[0] + a1[1];
    float B = A0 + dpp_movf<0xB1>(A1);   // xor1: quad_perm [1,0,3,2]
    B += dpp_movf<0x4E>(B);              // xor2: quad_perm [2,3,0,1]
    B += dpp_movf<0x128>(B);             // xor8: row_ror:8
    return B;
}

__global__ __launch_bounds__(512, 2)
void gru_fused(const float* __restrict__ x,     // [B,T,I]
               const float* __restrict__ W_ih,  // [3H,I]
               const float* __restrict__ W_hh,  // [3H,H]
               const float* __restrict__ b_ih,  // [3H]
               const float* __restrict__ b_hh,  // [3H]
               float* __restrict__ out)         // [B,H]
{
    const int b   = blockIdx.x;
    const int tid = threadIdx.x;
    const int wid = tid >> 6;
    const int l   = tid & 63;
    const int kt  = (l & 3) | ((l & 8) >> 1);         // bits 0,1,3 -> [0,8)
    const int jj  = ((l & 4) >> 2) | ((l & 48) >> 3); // bits 2,4,5 -> [0,8)
    const int l0  = l & 1;
    const int j0  = wid * 16 + jj * 2;
    const int jr  = j0 + l0;               // the row this lane finalizes
    const int kb  = kt * 16;               // k range [kb, kb+16)

    // h double buffer: chunk c holds h[16c..16c+16), padded to 20 floats.
    __shared__ __align__(16) float h_db[2][8][20];

    const float L2E = 1.4426950408889634f;   // log2(e)
    const float K2  = 2.0f * L2E;

    // ---- recurrent weights: [slot][k-pair], slot i <-> row j0+(i^l0) ----
    v2f wr[2][8], wz[2][8], wn[2][8];
    #pragma unroll
    for (int i = 0; i < 2; ++i) {
        const int row = j0 + (i ^ l0);
        const float* Wr = W_hh + (size_t)row * Hh + kb;
        const float* Wz = W_hh + (size_t)(Hh + row) * Hh + kb;
        const float* Wn = W_hh + (size_t)(2 * Hh + row) * Hh + kb;
        #pragma unroll
        for (int kk = 0; kk < 8; ++kk) {
            v2f a = *reinterpret_cast<const v2f*>(Wr + 2 * kk);
            a[0] *= L2E; a[1] *= L2E; wr[i][kk] = pinv(a);
            v2f c = *reinterpret_cast<const v2f*>(Wz + 2 * kk);
            c[0] *= L2E; c[1] *= L2E; wz[i][kk] = pinv(c);
            v2f d = *reinterpret_cast<const v2f*>(Wn + 2 * kk);
            d[0] *= K2;  d[1] *= K2;  wn[i][kk] = pinv(d);
        }
    }

    // ---- x-side: clamped window e0 = min(3kt,19), elems e0..e0+3 ----
    // kt<7 owns {3kt,3kt+1,3kt+2}: pair0=(w,w), pair1=(w,0)
    // kt=7 owns {21,22}, e0=19:     pair0=(0,0), pair1=(w21,w22)
    const int e0x = (kt < 7) ? 3 * kt : 19;
    const float m0 = (kt < 7) ? 1.0f : 0.0f;   // pair0 mask
    const float m3 = (kt < 7) ? 0.0f : 1.0f;   // pair1.hi mask
    v2f wxr[2][2], wxz[2][2], wxn[2][2];
    #pragma unroll
    for (int i = 0; i < 2; ++i) {
        const int row = j0 + (i ^ l0);
        const float* Xr = W_ih + (size_t)row * Ii + e0x;
        const float* Xz = W_ih + (size_t)(Hh + row) * Ii + e0x;
        const float* Xn = W_ih + (size_t)(2 * Hh + row) * Ii + e0x;
        v2f t;
        t[0] = Xr[0] * L2E * m0; t[1] = Xr[1] * L2E * m0; wxr[i][0] = pinv(t);
        t[0] = Xr[2] * L2E;      t[1] = Xr[3] * L2E * m3; wxr[i][1] = pinv(t);
        t[0] = Xz[0] * L2E * m0; t[1] = Xz[1] * L2E * m0; wxz[i][0] = pinv(t);
        t[0] = Xz[2] * L2E;      t[1] = Xz[3] * L2E * m3; wxz[i][1] = pinv(t);
        t[0] = Xn[0] * K2 * m0;  t[1] = Xn[1] * K2 * m0;  wxn[i][0] = pinv(t);
        t[0] = Xn[2] * K2;       t[1] = Xn[3] * K2 * m3;  wxn[i][1] = pinv(t);
    }

    // ---- biases for THIS lane's row jr (post-fold, prescaled) ----
    const float br  = pinf((b_ih[jr] + b_hh[jr]) * L2E);
    const float bz  = pinf((b_ih[Hh + jr] + b_hh[Hh + jr]) * L2E);
    const float bnh = pinf(b_hh[2 * Hh + jr] * K2);
    const float bnx = pinf(b_ih[2 * Hh + jr] * K2);

    const float* xptr = x + (size_t)b * Tt * Ii + e0x;  // lane-local x base

    // ---- init ----
    if (tid < Hh) h_db[0][tid >> 4][tid & 15] = 0.0f;
    // depth-2 x prefetch: qA serves even steps, qB odd steps.
    v4f qA = *reinterpret_cast<const v4fu*>(xptr);
    v4f qB = *reinterpret_cast<const v4fu*>(xptr + Ii);
    int xob = 2 * Ii;                      // element offset of row step+2
    float h_prev = 0.0f, acc_mean = 0.0f;
    const bool writer = ((l & 10) == 0);   // one writer per 4 duplicates
    bar_lds();

    auto body = [&](auto CUR, int s) {
        constexpr int cur = decltype(CUR)::v;
        const int step = s + cur;

        // ---- h reads FIRST: 4 x b128 (issue early, hide DS latency) ----
        const v4f hc0 = *reinterpret_cast<const v4f*>(&h_db[cur][kt][0]);
        const v4f hc1 = *reinterpret_cast<const v4f*>(&h_db[cur][kt][4]);
        const v4f hc2 = *reinterpret_cast<const v4f*>(&h_db[cur][kt][8]);
        const v4f hc3 = *reinterpret_cast<const v4f*>(&h_db[cur][kt][12]);

        // ---- x MACs (register-only, fills the DS-latency window) ----
        v2f xp0, xp1;
        if constexpr (cur == 0) {
            xp0[0] = qA[0]; xp0[1] = qA[1]; xp1[0] = qA[2]; xp1[1] = qA[3];
        } else {
            xp0[0] = qB[0]; xp0[1] = qB[1]; xp1[0] = qB[2]; xp1[1] = qB[3];
        }
        v2f ar0 = wxr[0][0] * xp0; ar0 = nfma(wxr[0][1], xp1, ar0);
        v2f ar1 = wxr[1][0] * xp0; ar1 = nfma(wxr[1][1], xp1, ar1);
        v2f az0 = wxz[0][0] * xp0; az0 = nfma(wxz[0][1], xp1, az0);
        v2f az1 = wxz[1][0] * xp0; az1 = nfma(wxz[1][1], xp1, az1);
        v2f ax0 = wxn[0][0] * xp0; ax0 = nfma(wxn[0][1], xp1, ax0);
        v2f ax1 = wxn[1][0] * xp0; ax1 = nfma(wxn[1][1], xp1, ax1);
        v2f an0; an0[0] = 0.0f; an0[1] = 0.0f;
        v2f an1; an1[0] = 0.0f; an1[1] = 0.0f;

        // ---- h MACs: 4 chunks x 12 pk (6 gate-chains x 2 pairs) ----
        #define HMAC(HC, C)                                                  \
        {                                                                    \
            v2f hpA; hpA[0] = (HC)[0]; hpA[1] = (HC)[1];                     \
            v2f hpB; hpB[0] = (HC)[2]; hpB[1] = (HC)[3];                     \
            ar0 = nfma(wr[0][2*(C)], hpA, ar0);                              \
            ar0 = nfma(wr[0][2*(C)+1], hpB, ar0);                            \
            ar1 = nfma(wr[1][2*(C)], hpA, ar1);                              \
            ar1 = nfma(wr[1][2*(C)+1], hpB, ar1);                            \
            az0 = nfma(wz[0][2*(C)], hpA, az0);                              \
            az0 = nfma(wz[0][2*(C)+1], hpB, az0);                            \
            az1 = nfma(wz[1][2*(C)], hpA, az1);                              \
            az1 = nfma(wz[1][2*(C)+1], hpB, az1);                            \
            an0 = nfma(wn[0][2*(C)], hpA, an0);                              \
            an0 = nfma(wn[0][2*(C)+1], hpB, an0);                            \
            an1 = nfma(wn[1][2*(C)], hpA, an1);                              \
            an1 = nfma(wn[1][2*(C)+1], hpB, an1);                            \
        }
        HMAC(hc0, 0) HMAC(hc1, 1) HMAC(hc2, 2) HMAC(hc3, 3)
        #undef HMAC

        // ---- reload this parity's x for step+2 (stays in flight) ----
        if constexpr (cur == 0) qA = *reinterpret_cast<const v4fu*>(xptr + xob);
        else                    qB = *reinterpret_cast<const v4fu*>(xptr + xob);
        if (step + 3 < Tt) xob += Ii;

        // ---- slot-packed DPP folds + biases: lane gets row jr's sums ----
        const float r_s = sfold(ar0, ar1) + br;
        const float z_s = sfold(az0, az1) + bz;
        const float ghn = sfold(an0, an1) + bnh;
        const float gxn = sfold(ax0, ax1) + bnx;

        // ---- lane-local epilogue (uniform over the 4 duplicate lanes) ----
        const float r  = __builtin_amdgcn_rcpf(1.0f + fexp2(-r_s));
        const float z  = __builtin_amdgcn_rcpf(1.0f + fexp2(-z_s));
        const float npre = fmaf(r, ghn, gxn);          // scaled by 2*log2e
        const float tt2  = __builtin_amdgcn_rcpf(1.0f + fexp2(-npre));
        const float nn   = fmaf(2.0f, tt2, -1.0f);     // tanh
        const float h_new = fmaf(z, h_prev - nn, nn);
        h_prev = h_new;
        acc_mean += h_new;
        if (writer) h_db[cur ^ 1][jr >> 4][jr & 15] = h_new;
        bar_lds();   // LDS-only barrier, once per step
    };

    for (int s = 0; s < Tt; s += 2) {
        body(ic<0>{}, s);
        body(ic<1>{}, s);
    }

    if (writer) out[(size_t)b * Hh + jr] = acc_mean * (1.0f / Tt);
}

extern "C" void kernel_launch(void* const* d_in, const int* in_sizes, int n_in,
                              void* d_out, int out_size, void* d_ws, size_t ws_size,
                              hipStream_t stream) {
    const float* x    = (const float*)d_in[0];
    const float* W_ih = (const float*)d_in[1];
    const float* W_hh = (const float*)d_in[2];
    const float* b_ih = (const float*)d_in[3];
    const float* b_hh = (const float*)d_in[4];
    float* out = (float*)d_out;

    gru_fused<<<Bb, 512, 0, stream>>>(x, W_ih, W_hh, b_ih, b_hh, out);
}